// Round 4
// baseline (626.339 us; speedup 1.0000x reference)
//
#include <hip/hip_runtime.h>

#define NPG 286
#define EPG 4000
#define NT 256
#define PAD 24            // padded-CSR slots per node (P(deg_in>24) ~ 0.003)
#define PADN 286          // pad node id; s_x4[286] == 0
#define PADW 0x011E011Eu  // two packed PADN u16s
#define SPILLCAP 128

// gather 24 padded src slots of one node: 3 conflict-free ds_read_b128 for the
// src ids (stride 48B -> lane bank-groups (3v+k)%8, uniform), then 24 x4 reads
__device__ __forceinline__ void gather24(const unsigned short* __restrict__ sp,
                                         const float4* __restrict__ x4,
                                         float& a0, float& a1, float& a2)
{
    const uint4* p = (const uint4*)sp;
    uint4 q0 = p[0], q1 = p[1], q2 = p[2];
    unsigned w[12] = { q0.x, q0.y, q0.z, q0.w,
                       q1.x, q1.y, q1.z, q1.w,
                       q2.x, q2.y, q2.z, q2.w };
    #pragma unroll
    for (int k = 0; k < 12; ++k) {
        float4 xa = x4[w[k] & 0xffffu];
        float4 xb = x4[w[k] >> 16];
        a0 += xa.x + xb.x;
        a1 += xa.y + xb.y;
        a2 += xa.z + xb.z;
    }
}

__global__ __launch_bounds__(NT, 6) void ppi_fused3(
    const float* __restrict__ feat,
    const int* __restrict__ src,
    const int* __restrict__ dst,
    const float* __restrict__ W1, const float* __restrict__ b1,
    const float* __restrict__ W2, const float* __restrict__ b2,
    const float* __restrict__ Wfc, const float* __restrict__ bfc,
    float* __restrict__ out)
{
    __shared__ __align__(16) unsigned short s_src[288 * PAD];  // 13824 B
    __shared__ float4 s_x4[288];                               // 4608 B
    __shared__ int s_cur[288];                                 // deg_in after build
    __shared__ int s_dgo[288];                                 // deg_out
    __shared__ unsigned s_spill[SPILLCAP];
    __shared__ int s_spillcnt;
    __shared__ float s_red[4];

    const int b = blockIdx.x, t = threadIdx.x;
    const long long eb = (long long)b * EPG;
    const int nb = b * NPG;

    // ---- phase 0: global loads (edges -> regs), LDS init, feat -> LDS
    unsigned pk[16];
    if (t < 250) {                       // 250*16 = 4000 edges
        const int4* s4 = (const int4*)(src + eb);
        const int4* d4 = (const int4*)(dst + eb);
        int4 se[4], de[4];
        #pragma unroll
        for (int r = 0; r < 4; ++r) { se[r] = s4[t * 4 + r]; de[r] = d4[t * 4 + r]; }
        #pragma unroll
        for (int r = 0; r < 4; ++r) {
            pk[r * 4 + 0] = ((unsigned)(de[r].x - nb) << 16) | (unsigned)(se[r].x - nb);
            pk[r * 4 + 1] = ((unsigned)(de[r].y - nb) << 16) | (unsigned)(se[r].y - nb);
            pk[r * 4 + 2] = ((unsigned)(de[r].z - nb) << 16) | (unsigned)(se[r].z - nb);
            pk[r * 4 + 3] = ((unsigned)(de[r].w - nb) << 16) | (unsigned)(se[r].w - nb);
        }
    }
    #pragma unroll
    for (int r = 0; r < 4; ++r) {        // 858 feat floats, coalesced
        int i = t + r * NT;
        if (i < NPG * 3) {
            float f = feat[(long long)nb * 3 + i];
            ((float*)s_x4)[(i / 3) * 4 + (i % 3)] = f;
        }
    }
    if (t < 2) s_x4[286 + t] = make_float4(0.f, 0.f, 0.f, 0.f);
    for (int i = t; i < 288 * PAD / 2; i += NT) ((unsigned*)s_src)[i] = PADW;
    for (int i = t; i < 288; i += NT) { s_cur[i] = 0; s_dgo[i] = 0; }
    if (t == 0) s_spillcnt = 0;

    // tiny weights -> uniform (scalar) regs
    float w1[9], w2[9], bb1[3], bb2[3];
    #pragma unroll
    for (int k = 0; k < 9; ++k) { w1[k] = W1[k]; w2[k] = W2[k]; }
    #pragma unroll
    for (int k = 0; k < 3; ++k) { bb1[k] = b1[k]; bb2[k] = b2[k]; }
    __syncthreads();

    // ---- phase 1: padded-CSR placement + out-degree histogram
    if (t < 250) {
        #pragma unroll
        for (int k = 0; k < 16; ++k) {
            int d = (int)(pk[k] >> 16), s = (int)(pk[k] & 0xffffu);
            atomicAdd(&s_dgo[s], 1);
            int pos = atomicAdd(&s_cur[d], 1);   // final value == deg_in
            if (pos < PAD) s_src[d * PAD + pos] = (unsigned short)s;
            else {
                int j = atomicAdd(&s_spillcnt, 1);
                if (j < SPILLCAP) s_spill[j] = pk[k];
            }
        }
    }
    __syncthreads();

    // ---- phase 2: norms into regs + prescale x by norm_out
    const int e1 = t >> 3;
    const bool has2 = ((t & 7) == 0) && (e1 < NPG - NT);   // 30 extra nodes
    const int v1 = NT + e1;
    float ni0, no0, ni1 = 0.f, no1 = 0.f;
    {
        int di = s_cur[t], dg = s_dgo[t];
        ni0 = rsqrtf((float)(di > 1 ? di : 1));
        no0 = rsqrtf((float)(dg > 1 ? dg : 1));
        float4 xv = s_x4[t];
        s_x4[t] = make_float4(xv.x * no0, xv.y * no0, xv.z * no0, 0.f);
    }
    if (has2) {
        int di = s_cur[v1], dg = s_dgo[v1];
        ni1 = rsqrtf((float)(di > 1 ? di : 1));
        no1 = rsqrtf((float)(dg > 1 ? dg : 1));
        float4 xv = s_x4[v1];
        s_x4[v1] = make_float4(xv.x * no1, xv.y * no1, xv.z * no1, 0.f);
    }
    int spn = s_spillcnt; if (spn > SPILLCAP) spn = SPILLCAP;
    __syncthreads();

    // ---- layer 1: gather -> regs, barrier, combine (pre-scale out by norm_out)
    float a0 = 0.f, a1 = 0.f, a2 = 0.f, c0 = 0.f, c1 = 0.f, c2 = 0.f;
    gather24(s_src + t * PAD, s_x4, a0, a1, a2);
    if (has2) gather24(s_src + v1 * PAD, s_x4, c0, c1, c2);
    for (int j = 0; j < spn; ++j) {
        unsigned e = s_spill[j];
        int d = (int)(e >> 16);
        if (d == t)            { float4 xs = s_x4[e & 0xffffu]; a0 += xs.x; a1 += xs.y; a2 += xs.z; }
        if (has2 && d == v1)   { float4 xs = s_x4[e & 0xffffu]; c0 += xs.x; c1 += xs.y; c2 += xs.z; }
    }
    __syncthreads();
    {
        float g0 = a0 * ni0, g1 = a1 * ni0, g2 = a2 * ni0;
        float o0 = fmaxf(fmaf(g0, w1[0], fmaf(g1, w1[3], fmaf(g2, w1[6], bb1[0]))), 0.f) * no0;
        float o1 = fmaxf(fmaf(g0, w1[1], fmaf(g1, w1[4], fmaf(g2, w1[7], bb1[1]))), 0.f) * no0;
        float o2 = fmaxf(fmaf(g0, w1[2], fmaf(g1, w1[5], fmaf(g2, w1[8], bb1[2]))), 0.f) * no0;
        s_x4[t] = make_float4(o0, o1, o2, 0.f);
        if (has2) {
            float h0 = c0 * ni1, h1 = c1 * ni1, h2 = c2 * ni1;
            float p0 = fmaxf(fmaf(h0, w1[0], fmaf(h1, w1[3], fmaf(h2, w1[6], bb1[0]))), 0.f) * no1;
            float p1 = fmaxf(fmaf(h0, w1[1], fmaf(h1, w1[4], fmaf(h2, w1[7], bb1[1]))), 0.f) * no1;
            float p2 = fmaxf(fmaf(h0, w1[2], fmaf(h1, w1[5], fmaf(h2, w1[8], bb1[2]))), 0.f) * no1;
            s_x4[v1] = make_float4(p0, p1, p2, 0.f);
        }
    }
    __syncthreads();

    // ---- layer 2: gather, barrier, combine (no out-scale)
    a0 = a1 = a2 = c0 = c1 = c2 = 0.f;
    gather24(s_src + t * PAD, s_x4, a0, a1, a2);
    if (has2) gather24(s_src + v1 * PAD, s_x4, c0, c1, c2);
    for (int j = 0; j < spn; ++j) {
        unsigned e = s_spill[j];
        int d = (int)(e >> 16);
        if (d == t)            { float4 xs = s_x4[e & 0xffffu]; a0 += xs.x; a1 += xs.y; a2 += xs.z; }
        if (has2 && d == v1)   { float4 xs = s_x4[e & 0xffffu]; c0 += xs.x; c1 += xs.y; c2 += xs.z; }
    }
    __syncthreads();
    {
        float g0 = a0 * ni0, g1 = a1 * ni0, g2 = a2 * ni0;
        float o0 = fmaxf(fmaf(g0, w2[0], fmaf(g1, w2[3], fmaf(g2, w2[6], bb2[0]))), 0.f);
        float o1 = fmaxf(fmaf(g0, w2[1], fmaf(g1, w2[4], fmaf(g2, w2[7], bb2[1]))), 0.f);
        float o2 = fmaxf(fmaf(g0, w2[2], fmaf(g1, w2[5], fmaf(g2, w2[8], bb2[2]))), 0.f);
        s_x4[t] = make_float4(o0, o1, o2, 0.f);
        if (has2) {
            float h0 = c0 * ni1, h1 = c1 * ni1, h2 = c2 * ni1;
            float p0 = fmaxf(fmaf(h0, w2[0], fmaf(h1, w2[3], fmaf(h2, w2[6], bb2[0]))), 0.f);
            float p1 = fmaxf(fmaf(h0, w2[1], fmaf(h1, w2[4], fmaf(h2, w2[7], bb2[1]))), 0.f);
            float p2 = fmaxf(fmaf(h0, w2[2], fmaf(h1, w2[5], fmaf(h2, w2[8], bb2[2]))), 0.f);
            s_x4[v1] = make_float4(p0, p1, p2, 0.f);
        }
    }
    __syncthreads();

    // ---- FC + sigmoid
    float partial;
    {
        float4 xv = s_x4[t];
        const float* wv = Wfc + 3 * t;
        partial = fmaf(xv.x, wv[0], fmaf(xv.y, wv[1], xv.z * wv[2]));
    }
    if (has2) {
        float4 xv = s_x4[v1];
        const float* wv = Wfc + 3 * v1;
        partial += fmaf(xv.x, wv[0], fmaf(xv.y, wv[1], xv.z * wv[2]));
    }
    #pragma unroll
    for (int off = 32; off > 0; off >>= 1) partial += __shfl_down(partial, off, 64);
    if ((t & 63) == 0) s_red[t >> 6] = partial;
    __syncthreads();
    if (t == 0) {
        float tot = s_red[0] + s_red[1] + s_red[2] + s_red[3] + bfc[0];
        out[b] = 1.f / (1.f + expf(-tot));
    }
}

extern "C" void kernel_launch(void* const* d_in, const int* in_sizes, int n_in,
                              void* d_out, int out_size, void* d_ws, size_t ws_size,
                              hipStream_t stream) {
    const float* feat = (const float*)d_in[0];
    const int* src = (const int*)d_in[1];
    const int* dst = (const int*)d_in[2];
    const float* W1 = (const float*)d_in[3];
    const float* b1 = (const float*)d_in[4];
    const float* W2 = (const float*)d_in[5];
    const float* b2 = (const float*)d_in[6];
    const float* Wfc = (const float*)d_in[7];
    const float* bfc = (const float*)d_in[8];
    float* out = (float*)d_out;

    const int B = out_size;  // 8192 graphs
    ppi_fused3<<<B, NT, 0, stream>>>(feat, src, dst, W1, b1, W2, b2, Wfc, bfc, out);
}